// Round 5
// baseline (187.927 us; speedup 1.0000x reference)
//
#include <hip/hip_runtime.h>
#include <stdint.h>

#define PRIME 1000003u
#define NORD  1000002u
#define KCH   16
#define BATCH 4
#define NPATCH 784
#define LLEN  9
#define IPMAX 9000          // |<x,y>| <= 20*50*9
#define TBLN  (2*IPMAX+1)
#define NBLK  128           // fused grid (all co-resident; 128 < 256 CUs)
#define TPB   832           // 13 waves

// Workspace offsets (bytes); ws is 256 MiB, we use ~2.1 MB.
#define FLAG_OFF  2000064   // 128 flags, 64 B apart (8192 B)
#define POOL_OFF  2008256   // float pooled [4][16][14][14]  (50176 B)
#define S2G_OFF   2058432   // float s2g    [4][32][7][7]    (25088 B)
#define S3G_OFF   2083520   // float s3g    [4][576]         (9216 B)

// Barrett: M = floor(2^41/p) = 2199016; exact for t < 2^40 with one cond-sub.
__device__ __forceinline__ uint32_t mmul(uint32_t a, uint32_t b) {
    uint64_t t = (uint64_t)a * (uint64_t)b;
    uint32_t q = (uint32_t)((t * 2199016ull) >> 41);
    uint32_t r = (uint32_t)t - q * PRIME;
    return (r >= PRIME) ? r - PRIME : r;
}

__device__ __forceinline__ uint32_t mpow(uint32_t base, uint32_t exp) {
    uint32_t r = 1u, b = base;
    while (exp) {
        if (exp & 1u) r = mmul(r, b);
        b = mmul(b, b);
        exp >>= 1;
    }
    return r;
}

// ---- Fence-free cross-phase data access (validated rounds 2-3: absmax 0) ---
// Relaxed agent-scope atomics compile to coherent accesses; stores are at the
// device coherence point once vmcnt retires them (which the compiler-inserted
// s_waitcnt vmcnt(0) before s_barrier guarantees at each __syncthreads).
__device__ __forceinline__ void cstore(float* p, float v) {
    __hip_atomic_store(p, v, __ATOMIC_RELAXED, __HIP_MEMORY_SCOPE_AGENT);
}
__device__ __forceinline__ float cload(const float* p) {
    return __hip_atomic_load(p, __ATOMIC_RELAXED, __HIP_MEMORY_SCOPE_AGENT);
}

// ---- Flag-per-block grid barrier (zero atomic-RMW) -------------------------
// Round-3 residue was arrive-RMW serialization (~100ns per same-line RMW).
// Here each block STOREs its monotone phase number to its own cache line:
// 128 stores to 128 distinct lines proceed in parallel (no serialization).
// Waiter = single scalar thread doing a monotone scan (round-3-proven poll
// pattern): flags only increase, so each flag is polled until it first
// reaches the target, then never re-read. Flags zeroed by build_table.
__device__ __forceinline__ void set_flag(unsigned* flags, int bid, unsigned phase) {
    __syncthreads();   // all block stores vmcnt-retired before the flag store
    if (threadIdx.x == 0)
        __hip_atomic_store(&flags[bid * 16], phase,
                           __ATOMIC_RELAXED, __HIP_MEMORY_SCOPE_AGENT);
}
__device__ __forceinline__ void wait_flags(unsigned* flags, int n, unsigned phase) {
    if (threadIdx.x == 0) {
        int i = 0;
        while (i < n) {
            if (__hip_atomic_load(&flags[i * 16],
                                  __ATOMIC_RELAXED, __HIP_MEMORY_SCOPE_AGENT) >= phase) {
                i++;
            } else {
                __builtin_amdgcn_s_sleep(8);
            }
        }
    }
    __syncthreads();
}

// ---------------- Kernel 1: dlog lookup table (int16) -----------------------
// table[g^e mod p] = e for e in [-9000,9000]. Only queried entries are ever
// written (decrypted values are guaranteed g^e). Also zeroes the 128 flags
// (ws is re-poisoned between iterations; the kernel boundary orders this).
__global__ void build_table(const int* __restrict__ g_in, int16_t* __restrict__ table,
                            unsigned* __restrict__ flags) {
    int e = blockIdx.x * blockDim.x + threadIdx.x;
    if (e >= TBLN) return;
    if (e < NBLK)
        __hip_atomic_store(&flags[e * 16], 0u, __ATOMIC_RELAXED, __HIP_MEMORY_SCOPE_AGENT);
    int es = e - IPMAX;
    uint32_t exp = (es >= 0) ? (uint32_t)es : (uint32_t)(es + (int)NORD);
    table[mpow((uint32_t)g_in[0], exp)] = (int16_t)es;
}

// ---------------- Kernel 2: fused pipeline ----------------------------------
// 128 blocks x 832 threads. Phases (flag value after arrival):
//   A: decrypt+bn1+relu+pool, block=(k,b,half: 14 rows)  all 128    -> 1
//   B: conv2+bn2+relu+pool, 4 oc/block                   blocks<32  -> 2
//   C: conv3+bn3+relu+pool, 4 oc/block                   blocks<64  -> 3
//   D: fc1+relu+fc2, one block per batch                 blocks<4
__global__ void __launch_bounds__(TPB) fused(
    const int* __restrict__ ct0, const int* __restrict__ cts,
    const int* __restrict__ y, const int* __restrict__ sk_y,
    const float* __restrict__ bias1,
    const float* __restrict__ bn1_g, const float* __restrict__ bn1_b,
    const float* __restrict__ bn1_m, const float* __restrict__ bn1_v,
    const float* __restrict__ conv2_w, const float* __restrict__ conv2_b,
    const float* __restrict__ bn2_g, const float* __restrict__ bn2_b,
    const float* __restrict__ bn2_m, const float* __restrict__ bn2_v,
    const float* __restrict__ conv3_w, const float* __restrict__ conv3_b,
    const float* __restrict__ bn3_g, const float* __restrict__ bn3_b,
    const float* __restrict__ bn3_m, const float* __restrict__ bn3_v,
    const float* __restrict__ fc1_w, const float* __restrict__ fc1_b,
    const float* __restrict__ fc2_w, const float* __restrict__ fc2_b,
    const int16_t* __restrict__ table,
    float* __restrict__ pooled, float* __restrict__ s2g, float* __restrict__ s3g,
    float* __restrict__ out, unsigned* __restrict__ flags) {

    __shared__ union {
        float raw[392];                                                        // A: 1.6 KB
        struct { float s1p[16][16][16]; float w[4][144]; float co[4][196]; } c2; // 21.4 KB
        struct { float s2p[32][9][9];  float w[4][288]; float co[4][49]; } c3;   // 15.4 KB
        struct { float s3[576]; float h[128]; } d;                             // 2.8 KB
    } sm;

    const int bid = blockIdx.x;
    const int tid = threadIdx.x;

    // ---------------- Phase A: decrypt + bn1 + relu + pool(28->14) ---------
    // block = (k, b, half): half = rows 0..13 or 14..27 (392 patches).
    // 128 CUs active; per-CU VALU work halved vs the round-3 64-block split.
    {
        const int pair = bid >> 1, half = bid & 1;
        const int k = pair & 15, b = pair >> 4;
        const int* yrow = y + k * LLEN;
        int yv[LLEN];
#pragma unroll
        for (int i = 0; i < LLEN; i++) yv[i] = yrow[i];      // scalar loads
        const uint32_t sk = (uint32_t)sk_y[k];
        const float sc  = bn1_g[k] * rsqrtf(bn1_v[k] + 1e-5f);
        const float shf = (bias1[k] - bn1_m[k]) * sc + bn1_b[k];

        if (tid < 392) {
            const int j = half * 392 + tid;
            const int* crow = cts + ((b * NPATCH) + j) * LLEN;
            uint32_t c[LLEN];
#pragma unroll
            for (int i = 0; i < LLEN; i++) c[i] = (uint32_t)crow[i];

            // Shamir: |y_i| <= 50 < 64 (6 bits). Branch conds block-uniform.
            uint32_t accp = 1u, accn = 1u;
#pragma unroll
            for (int bit = 5; bit >= 0; bit--) {
                accp = mmul(accp, accp);
                accn = mmul(accn, accn);
#pragma unroll
                for (int i = 0; i < LLEN; i++) {
                    int yi = yv[i];
                    int ay = (yi > 0) ? yi : -yi;
                    if ((ay >> bit) & 1) {
                        if (yi > 0) accp = mmul(accp, c[i]);
                        else        accn = mmul(accn, c[i]);
                    }
                }
            }

            uint32_t den = mpow((uint32_t)ct0[b * NPATCH + j], sk);
            den = mmul(den, accn);
            uint32_t val = mmul(accp, mpow(den, PRIME - 2u));  // const exp: unrolls

            int ip = (int)table[val];              // guaranteed hit, |ip|<=9000
            float v_ = fmaf((float)ip, sc * 1e-4f, shf);
            sm.raw[tid] = fmaxf(v_, 0.0f);         // 14 rows x 28 cols
        }
        __syncthreads();
        if (tid < 98) {                            // pool 14x28 -> 7x14
            int pyl = tid / 14, px = tid % 14;
            const float* r0 = &sm.raw[(2 * pyl) * 28 + 2 * px];
            float m = fmaxf(fmaxf(r0[0], r0[1]), fmaxf(r0[28], r0[29]));
            cstore(&pooled[((b * KCH) + k) * 196 + (half * 7 + pyl) * 14 + px], m);
        }
    }
    set_flag(flags, bid, 1u);
    if (bid >= 64) return;

    // ---------------- Phase B: conv2 + bn2 + relu + pool(14->7), 4 oc ------
    if (bid < 32) {
        wait_flags(flags, NBLK, 1u);
        const int b = bid >> 3, base_oc = (bid & 7) * 4;

        for (int i = tid; i < 16 * 16 * 16; i += TPB)
            ((float*)sm.c2.s1p)[i] = 0.0f;
        if (tid < 576) sm.c2.w[tid / 144][tid % 144] =
            conv2_w[(base_oc + tid / 144) * 144 + tid % 144];
        __syncthreads();
        for (int i = tid; i < 16 * 196; i += TPB) {
            int ic = i / 196, pos = i % 196;
            int yy = pos / 14, xx = pos % 14;
            sm.c2.s1p[ic][yy + 1][xx + 1] = cload(&pooled[((b * KCH) + ic) * 196 + pos]);
        }
        __syncthreads();

        if (tid < 784) {                           // 4 oc x 196 positions
            int ocs = tid / 196, pos = tid % 196;
            int oh = pos / 14, ow = pos % 14;
            int oc = base_oc + ocs;
            float a0 = 0.0f, a1 = 0.0f, a2 = 0.0f;
#pragma unroll
            for (int ic = 0; ic < 16; ic++) {
                const float* wp = &sm.c2.w[ocs][ic * 9];
                const float* sp = &sm.c2.s1p[ic][oh][ow];
                a0 = fmaf(sp[0],  wp[0], fmaf(sp[1],  wp[1], fmaf(sp[2],  wp[2], a0)));
                a1 = fmaf(sp[16], wp[3], fmaf(sp[17], wp[4], fmaf(sp[18], wp[5], a1)));
                a2 = fmaf(sp[32], wp[6], fmaf(sp[33], wp[7], fmaf(sp[34], wp[8], a2)));
            }
            float sc = bn2_g[oc] * rsqrtf(bn2_v[oc] + 1e-5f);
            float shf = bn2_b[oc] - bn2_m[oc] * sc;
            sm.c2.co[ocs][pos] = fmaxf((a0 + a1 + a2 + conv2_b[oc]) * sc + shf, 0.0f);
        }
        __syncthreads();

        if (tid < 196) {                           // 4 oc x 49 pooled outputs
            int ocs = tid / 49, pp = tid % 49;
            int oh = pp / 7, ow = pp % 7;
            const float* c0 = &sm.c2.co[ocs][(2 * oh) * 14 + 2 * ow];
            cstore(&s2g[((b * 32 + base_oc + ocs) * 49) + pp],
                   fmaxf(fmaxf(c0[0], c0[1]), fmaxf(c0[14], c0[15])));
        }
        set_flag(flags, bid, 2u);
    }

    // ---------------- Phase C: conv3 + bn3 + relu + pool(7->3), 4 oc -------
    {
        wait_flags(flags, 32, 2u);
        const int b = bid >> 4, ocg = bid & 15;

        for (int i = tid; i < 32 * 81; i += TPB)
            ((float*)sm.c3.s2p)[i] = 0.0f;
        for (int i = tid; i < 4 * 288; i += TPB) {
            int w2 = i / 288, rr = i % 288;
            sm.c3.w[w2][rr] = conv3_w[(ocg * 4 + w2) * 288 + rr];
        }
        __syncthreads();
        for (int i = tid; i < 32 * 49; i += TPB) {
            int ic = i / 49, pos = i % 49;
            sm.c3.s2p[ic][pos / 7 + 1][pos % 7 + 1] = cload(&s2g[((b * 32 + ic) * 49) + pos]);
        }
        __syncthreads();

        const int wid = tid >> 6, lane = tid & 63;
        if (wid < 4 && lane < 49) {
            int oh = lane / 7, ow = lane % 7;
            float a0 = 0.0f, a1 = 0.0f, a2 = 0.0f;
#pragma unroll
            for (int ic = 0; ic < 32; ic++) {
                const float* wp = &sm.c3.w[wid][ic * 9];
                const float* sp = &sm.c3.s2p[ic][oh][ow];
                a0 = fmaf(sp[0],  wp[0], fmaf(sp[1],  wp[1], fmaf(sp[2],  wp[2], a0)));
                a1 = fmaf(sp[9],  wp[3], fmaf(sp[10], wp[4], fmaf(sp[11], wp[5], a1)));
                a2 = fmaf(sp[18], wp[6], fmaf(sp[19], wp[7], fmaf(sp[20], wp[8], a2)));
            }
            int oc = ocg * 4 + wid;
            float sc = bn3_g[oc] * rsqrtf(bn3_v[oc] + 1e-5f);
            float shf = bn3_b[oc] - bn3_m[oc] * sc;
            sm.c3.co[wid][lane] = fmaxf((a0 + a1 + a2 + conv3_b[oc]) * sc + shf, 0.0f);
        }
        __syncthreads();

        if (tid < 36) {
            int w2 = tid / 9, p = tid % 9;
            int oh = p / 3, ow = p % 3;
            const float* c0 = &sm.c3.co[w2][(2 * oh) * 7 + 2 * ow];
            cstore(&s3g[b * 576 + (ocg * 4 + w2) * 9 + p],
                   fmaxf(fmaxf(c0[0], c0[1]), fmaxf(c0[7], c0[8])));
        }
        set_flag(flags, bid, 3u);
    }
    if (bid >= BATCH) return;

    // ---------------- Phase D: fc1 + relu + fc2 (one block per batch) ------
    {
        wait_flags(flags, 64, 3u);
        const int b = bid;
        if (tid < 576) sm.d.s3[tid] = cload(&s3g[b * 576 + tid]);
        __syncthreads();

        const int wid = tid >> 6, lane = tid & 63;
        for (int o = wid; o < 128; o += 13) {      // 13 waves cover 128 outputs
            const float* w = fc1_w + o * 576;
            float acc = 0.0f;
#pragma unroll
            for (int jj = 0; jj < 9; jj++)         // lanes across 576: coalesced
                acc = fmaf(sm.d.s3[jj * 64 + lane], w[jj * 64 + lane], acc);
#pragma unroll
            for (int off = 32; off; off >>= 1) acc += __shfl_down(acc, off);
            if (lane == 0) sm.d.h[o] = fmaxf(acc + fc1_b[o], 0.0f);
        }
        __syncthreads();

        if (wid < 10) {
            const float* w = fc2_w + wid * 128;
            float acc = fmaf(sm.d.h[lane], w[lane], 0.0f);
            acc = fmaf(sm.d.h[64 + lane], w[64 + lane], acc);
#pragma unroll
            for (int off = 32; off; off >>= 1) acc += __shfl_down(acc, off);
            if (lane == 0) out[b * 10 + wid] = acc + fc2_b[wid];
        }
    }
}

extern "C" void kernel_launch(void* const* d_in, const int* in_sizes, int n_in,
                              void* d_out, int out_size, void* d_ws, size_t ws_size,
                              hipStream_t stream) {
    const int*   ct0    = (const int*)d_in[0];
    const int*   cts    = (const int*)d_in[1];
    const int*   y      = (const int*)d_in[2];
    const int*   sk_y   = (const int*)d_in[3];
    const float* bias1  = (const float*)d_in[4];
    const float* bn1_g  = (const float*)d_in[5];
    const float* bn1_b  = (const float*)d_in[6];
    const float* bn1_m  = (const float*)d_in[7];
    const float* bn1_v  = (const float*)d_in[8];
    const float* conv2_w = (const float*)d_in[9];
    const float* conv2_b = (const float*)d_in[10];
    const float* bn2_g  = (const float*)d_in[11];
    const float* bn2_b  = (const float*)d_in[12];
    const float* bn2_m  = (const float*)d_in[13];
    const float* bn2_v  = (const float*)d_in[14];
    const float* conv3_w = (const float*)d_in[15];
    const float* conv3_b = (const float*)d_in[16];
    const float* bn3_g  = (const float*)d_in[17];
    const float* bn3_b  = (const float*)d_in[18];
    const float* bn3_m  = (const float*)d_in[19];
    const float* bn3_v  = (const float*)d_in[20];
    const float* fc1_w  = (const float*)d_in[21];
    const float* fc1_b  = (const float*)d_in[22];
    const float* fc2_w  = (const float*)d_in[23];
    const float* fc2_b  = (const float*)d_in[24];
    const int*   g_in   = (const int*)d_in[25];
    float* out = (float*)d_out;

    char* ws = (char*)d_ws;
    int16_t*  table  = (int16_t*)ws;
    unsigned* flags  = (unsigned*)(ws + FLAG_OFF);
    float* pooled = (float*)(ws + POOL_OFF);
    float* s2g    = (float*)(ws + S2G_OFF);
    float* s3g    = (float*)(ws + S3G_OFF);

    build_table<<<(TBLN + 255) / 256, 256, 0, stream>>>(g_in, table, flags);

    fused<<<NBLK, TPB, 0, stream>>>(
        ct0, cts, y, sk_y, bias1, bn1_g, bn1_b, bn1_m, bn1_v,
        conv2_w, conv2_b, bn2_g, bn2_b, bn2_m, bn2_v,
        conv3_w, conv3_b, bn3_g, bn3_b, bn3_m, bn3_v,
        fc1_w, fc1_b, fc2_w, fc2_b, table, pooled, s2g, s3g, out, flags);
}

// Round 6
// 140.074 us; speedup vs baseline: 1.3416x; 1.3416x over previous
//
#include <hip/hip_runtime.h>
#include <stdint.h>

#define PRIME 1000003u
#define NORD  1000002u
#define KCH   16
#define BATCH 4
#define NPATCH 784
#define LLEN  9
#define IPMAX 9000          // |<x,y>| <= 20*50*9
#define TBLN  (2*IPMAX+1)
#define NBLK  128           // fused grid (all co-resident; 128 < 256 CUs)
#define TPB   832           // 13 waves

// Workspace offsets (bytes); ws is 256 MiB, we use ~2.1 MB.
#define FLAG_OFF  2000064   // 128 flags, 64 B apart (8192 B)
#define POOL_OFF  2008256   // float pooled [4][16][14][14]  (50176 B)
#define S2G_OFF   2058432   // float s2g    [4][32][7][7]    (25088 B)
#define S3G_OFF   2083520   // float s3g    [4][576]         (9216 B)

// Barrett: M = floor(2^41/p) = 2199016; exact for t < 2^40 with one cond-sub.
__device__ __forceinline__ uint32_t mmul(uint32_t a, uint32_t b) {
    uint64_t t = (uint64_t)a * (uint64_t)b;
    uint32_t q = (uint32_t)((t * 2199016ull) >> 41);
    uint32_t r = (uint32_t)t - q * PRIME;
    return (r >= PRIME) ? r - PRIME : r;
}

__device__ __forceinline__ uint32_t mpow(uint32_t base, uint32_t exp) {
    uint32_t r = 1u, b = base;
    while (exp) {
        if (exp & 1u) r = mmul(r, b);
        b = mmul(b, b);
        exp >>= 1;
    }
    return r;
}

// ---- Fence-free cross-phase data access (validated rounds 2-5: absmax 0) ---
// Relaxed agent-scope atomics compile to coherent accesses; stores are at the
// device coherence point once vmcnt retires them (which the compiler-inserted
// s_waitcnt vmcnt(0) before s_barrier guarantees at each __syncthreads).
__device__ __forceinline__ void cstore(float* p, float v) {
    __hip_atomic_store(p, v, __ATOMIC_RELAXED, __HIP_MEMORY_SCOPE_AGENT);
}
__device__ __forceinline__ float cload(const float* p) {
    return __hip_atomic_load(p, __ATOMIC_RELAXED, __HIP_MEMORY_SCOPE_AGENT);
}

// ---- Flag-per-block grid barrier, memory-parallel waiter -------------------
// Arrive: each block STOREs its monotone phase number to its own cache line
// (128 stores to 128 distinct lines, parallel, zero RMW — validated r5).
// Round-5 lesson: a serial scan waiter costs n x load-latency (~27us for
// n=128). Here the FIRST WAVE polls: lane i loads flags[i] and flags[i+64]
// (all <=128 loads in flight at once -> ONE miss latency per poll round),
// exit decided by __all -> wave-uniform branch, no divergent spin.
__device__ __forceinline__ void set_flag(unsigned* flags, int bid, unsigned phase) {
    __syncthreads();   // all block stores vmcnt-retired before the flag store
    if (threadIdx.x == 0)
        __hip_atomic_store(&flags[bid * 16], phase,
                           __ATOMIC_RELAXED, __HIP_MEMORY_SCOPE_AGENT);
}
__device__ __forceinline__ void wait_all(unsigned* flags, int n, unsigned phase) {
    if (threadIdx.x < 64) {
        const int lane = threadIdx.x;
        for (;;) {
            unsigned f0 = (lane < n)
                ? __hip_atomic_load(&flags[lane * 16],
                                    __ATOMIC_RELAXED, __HIP_MEMORY_SCOPE_AGENT) : ~0u;
            unsigned f1 = (lane + 64 < n)
                ? __hip_atomic_load(&flags[(lane + 64) * 16],
                                    __ATOMIC_RELAXED, __HIP_MEMORY_SCOPE_AGENT) : ~0u;
            if (__all(f0 >= phase && f1 >= phase)) break;
            __builtin_amdgcn_s_sleep(2);
        }
    }
    __syncthreads();
}

// ---------------- Kernel 1: dlog lookup table (int16) -----------------------
// table[g^e mod p] = e for e in [-9000,9000]. Only queried entries are ever
// written (decrypted values are guaranteed g^e). Also zeroes the 128 flags
// (ws is re-poisoned between iterations; the kernel boundary orders this).
__global__ void build_table(const int* __restrict__ g_in, int16_t* __restrict__ table,
                            unsigned* __restrict__ flags) {
    int e = blockIdx.x * blockDim.x + threadIdx.x;
    if (e >= TBLN) return;
    if (e < NBLK)
        __hip_atomic_store(&flags[e * 16], 0u, __ATOMIC_RELAXED, __HIP_MEMORY_SCOPE_AGENT);
    int es = e - IPMAX;
    uint32_t exp = (es >= 0) ? (uint32_t)es : (uint32_t)(es + (int)NORD);
    table[mpow((uint32_t)g_in[0], exp)] = (int16_t)es;
}

// ---------------- Kernel 2: fused pipeline ----------------------------------
// 128 blocks x 832 threads. Phases (flag value after arrival):
//   A: decrypt+bn1+relu+pool, block=(k,b,half: 14 rows)  all 128    -> 1
//   B: conv2+bn2+relu+pool, 4 oc/block                   blocks<32  -> 2
//   C: conv3+bn3+relu+pool, 4 oc/block                   blocks<64  -> 3
//   D: fc1+relu+fc2, one block per batch                 blocks<4
// Input-independent LDS prep (halo zero, weight loads) is issued BEFORE each
// wait_all to overlap the producer's tail; the wait's trailing __syncthreads
// orders it vs the dependent staging, and the preceding set_flag's
// __syncthreads orders LDS-union reuse.
__global__ void __launch_bounds__(TPB) fused(
    const int* __restrict__ ct0, const int* __restrict__ cts,
    const int* __restrict__ y, const int* __restrict__ sk_y,
    const float* __restrict__ bias1,
    const float* __restrict__ bn1_g, const float* __restrict__ bn1_b,
    const float* __restrict__ bn1_m, const float* __restrict__ bn1_v,
    const float* __restrict__ conv2_w, const float* __restrict__ conv2_b,
    const float* __restrict__ bn2_g, const float* __restrict__ bn2_b,
    const float* __restrict__ bn2_m, const float* __restrict__ bn2_v,
    const float* __restrict__ conv3_w, const float* __restrict__ conv3_b,
    const float* __restrict__ bn3_g, const float* __restrict__ bn3_b,
    const float* __restrict__ bn3_m, const float* __restrict__ bn3_v,
    const float* __restrict__ fc1_w, const float* __restrict__ fc1_b,
    const float* __restrict__ fc2_w, const float* __restrict__ fc2_b,
    const int16_t* __restrict__ table,
    float* __restrict__ pooled, float* __restrict__ s2g, float* __restrict__ s3g,
    float* __restrict__ out, unsigned* __restrict__ flags) {

    __shared__ union {
        float raw[392];                                                        // A: 1.6 KB
        struct { float s1p[16][16][16]; float w[4][144]; float co[4][196]; } c2; // 21.4 KB
        struct { float s2p[32][9][9];  float w[4][288]; float co[4][49]; } c3;   // 15.4 KB
        struct { float s3[576]; float h[128]; } d;                             // 2.8 KB
    } sm;

    const int bid = blockIdx.x;
    const int tid = threadIdx.x;

    // ---------------- Phase A: decrypt + bn1 + relu + pool(28->14) ---------
    // block = (k, b, half): half = rows 0..13 or 14..27 (392 patches).
    {
        const int pair = bid >> 1, half = bid & 1;
        const int k = pair & 15, b = pair >> 4;
        const int* yrow = y + k * LLEN;
        int yv[LLEN];
#pragma unroll
        for (int i = 0; i < LLEN; i++) yv[i] = yrow[i];      // scalar loads
        const uint32_t sk = (uint32_t)sk_y[k];
        const float sc  = bn1_g[k] * rsqrtf(bn1_v[k] + 1e-5f);
        const float shf = (bias1[k] - bn1_m[k]) * sc + bn1_b[k];

        if (tid < 392) {
            const int j = half * 392 + tid;
            const int* crow = cts + ((b * NPATCH) + j) * LLEN;
            uint32_t c[LLEN];
#pragma unroll
            for (int i = 0; i < LLEN; i++) c[i] = (uint32_t)crow[i];

            // Shamir: |y_i| <= 50 < 64 (6 bits). Branch conds block-uniform.
            uint32_t accp = 1u, accn = 1u;
#pragma unroll
            for (int bit = 5; bit >= 0; bit--) {
                accp = mmul(accp, accp);
                accn = mmul(accn, accn);
#pragma unroll
                for (int i = 0; i < LLEN; i++) {
                    int yi = yv[i];
                    int ay = (yi > 0) ? yi : -yi;
                    if ((ay >> bit) & 1) {
                        if (yi > 0) accp = mmul(accp, c[i]);
                        else        accn = mmul(accn, c[i]);
                    }
                }
            }

            uint32_t den = mpow((uint32_t)ct0[b * NPATCH + j], sk);
            den = mmul(den, accn);
            uint32_t val = mmul(accp, mpow(den, PRIME - 2u));  // const exp: unrolls

            int ip = (int)table[val];              // guaranteed hit, |ip|<=9000
            float v_ = fmaf((float)ip, sc * 1e-4f, shf);
            sm.raw[tid] = fmaxf(v_, 0.0f);         // 14 rows x 28 cols
        }
        __syncthreads();
        if (tid < 98) {                            // pool 14x28 -> 7x14
            int pyl = tid / 14, px = tid % 14;
            const float* r0 = &sm.raw[(2 * pyl) * 28 + 2 * px];
            float m = fmaxf(fmaxf(r0[0], r0[1]), fmaxf(r0[28], r0[29]));
            cstore(&pooled[((b * KCH) + k) * 196 + (half * 7 + pyl) * 14 + px], m);
        }
    }
    set_flag(flags, bid, 1u);
    if (bid >= 64) return;

    // ---------------- Phase B: conv2 + bn2 + relu + pool(14->7), 4 oc ------
    if (bid < 32) {
        const int b = bid >> 3, base_oc = (bid & 7) * 4;

        // prep (input-independent): halo zero + weights, before the wait
        for (int i = tid; i < 16 * 16 * 16; i += TPB)
            ((float*)sm.c2.s1p)[i] = 0.0f;
        if (tid < 576) sm.c2.w[tid / 144][tid % 144] =
            conv2_w[(base_oc + tid / 144) * 144 + tid % 144];

        wait_all(flags, NBLK, 1u);                 // ends with __syncthreads

        for (int i = tid; i < 16 * 196; i += TPB) {
            int ic = i / 196, pos = i % 196;
            int yy = pos / 14, xx = pos % 14;
            sm.c2.s1p[ic][yy + 1][xx + 1] = cload(&pooled[((b * KCH) + ic) * 196 + pos]);
        }
        __syncthreads();

        if (tid < 784) {                           // 4 oc x 196 positions
            int ocs = tid / 196, pos = tid % 196;
            int oh = pos / 14, ow = pos % 14;
            int oc = base_oc + ocs;
            float a0 = 0.0f, a1 = 0.0f, a2 = 0.0f;
#pragma unroll
            for (int ic = 0; ic < 16; ic++) {
                const float* wp = &sm.c2.w[ocs][ic * 9];
                const float* sp = &sm.c2.s1p[ic][oh][ow];
                a0 = fmaf(sp[0],  wp[0], fmaf(sp[1],  wp[1], fmaf(sp[2],  wp[2], a0)));
                a1 = fmaf(sp[16], wp[3], fmaf(sp[17], wp[4], fmaf(sp[18], wp[5], a1)));
                a2 = fmaf(sp[32], wp[6], fmaf(sp[33], wp[7], fmaf(sp[34], wp[8], a2)));
            }
            float sc = bn2_g[oc] * rsqrtf(bn2_v[oc] + 1e-5f);
            float shf = bn2_b[oc] - bn2_m[oc] * sc;
            sm.c2.co[ocs][pos] = fmaxf((a0 + a1 + a2 + conv2_b[oc]) * sc + shf, 0.0f);
        }
        __syncthreads();

        if (tid < 196) {                           // 4 oc x 49 pooled outputs
            int ocs = tid / 49, pp = tid % 49;
            int oh = pp / 7, ow = pp % 7;
            const float* c0 = &sm.c2.co[ocs][(2 * oh) * 14 + 2 * ow];
            cstore(&s2g[((b * 32 + base_oc + ocs) * 49) + pp],
                   fmaxf(fmaxf(c0[0], c0[1]), fmaxf(c0[14], c0[15])));
        }
        set_flag(flags, bid, 2u);
    }

    // ---------------- Phase C: conv3 + bn3 + relu + pool(7->3), 4 oc -------
    {
        const int b = bid >> 4, ocg = bid & 15;

        // prep (input-independent): halo zero + weights, before the wait.
        // For blocks 0..31 the preceding set_flag(2)'s __syncthreads orders
        // the LDS-union reuse; blocks 32..63 come straight from set_flag(1).
        for (int i = tid; i < 32 * 81; i += TPB)
            ((float*)sm.c3.s2p)[i] = 0.0f;
        for (int i = tid; i < 4 * 288; i += TPB) {
            int w2 = i / 288, rr = i % 288;
            sm.c3.w[w2][rr] = conv3_w[(ocg * 4 + w2) * 288 + rr];
        }

        wait_all(flags, 32, 2u);                   // ends with __syncthreads

        for (int i = tid; i < 32 * 49; i += TPB) {
            int ic = i / 49, pos = i % 49;
            sm.c3.s2p[ic][pos / 7 + 1][pos % 7 + 1] = cload(&s2g[((b * 32 + ic) * 49) + pos]);
        }
        __syncthreads();

        const int wid = tid >> 6, lane = tid & 63;
        if (wid < 4 && lane < 49) {
            int oh = lane / 7, ow = lane % 7;
            float a0 = 0.0f, a1 = 0.0f, a2 = 0.0f;
#pragma unroll
            for (int ic = 0; ic < 32; ic++) {
                const float* wp = &sm.c3.w[wid][ic * 9];
                const float* sp = &sm.c3.s2p[ic][oh][ow];
                a0 = fmaf(sp[0],  wp[0], fmaf(sp[1],  wp[1], fmaf(sp[2],  wp[2], a0)));
                a1 = fmaf(sp[9],  wp[3], fmaf(sp[10], wp[4], fmaf(sp[11], wp[5], a1)));
                a2 = fmaf(sp[18], wp[6], fmaf(sp[19], wp[7], fmaf(sp[20], wp[8], a2)));
            }
            int oc = ocg * 4 + wid;
            float sc = bn3_g[oc] * rsqrtf(bn3_v[oc] + 1e-5f);
            float shf = bn3_b[oc] - bn3_m[oc] * sc;
            sm.c3.co[wid][lane] = fmaxf((a0 + a1 + a2 + conv3_b[oc]) * sc + shf, 0.0f);
        }
        __syncthreads();

        if (tid < 36) {
            int w2 = tid / 9, p = tid % 9;
            int oh = p / 3, ow = p % 3;
            const float* c0 = &sm.c3.co[w2][(2 * oh) * 7 + 2 * ow];
            cstore(&s3g[b * 576 + (ocg * 4 + w2) * 9 + p],
                   fmaxf(fmaxf(c0[0], c0[1]), fmaxf(c0[7], c0[8])));
        }
        set_flag(flags, bid, 3u);
    }
    if (bid >= BATCH) return;

    // ---------------- Phase D: fc1 + relu + fc2 (one block per batch) ------
    {
        wait_all(flags, 64, 3u);
        const int b = bid;
        if (tid < 576) sm.d.s3[tid] = cload(&s3g[b * 576 + tid]);
        __syncthreads();

        const int wid = tid >> 6, lane = tid & 63;
        for (int o = wid; o < 128; o += 13) {      // 13 waves cover 128 outputs
            const float* w = fc1_w + o * 576;
            float acc = 0.0f;
#pragma unroll
            for (int jj = 0; jj < 9; jj++)         // lanes across 576: coalesced
                acc = fmaf(sm.d.s3[jj * 64 + lane], w[jj * 64 + lane], acc);
#pragma unroll
            for (int off = 32; off; off >>= 1) acc += __shfl_down(acc, off);
            if (lane == 0) sm.d.h[o] = fmaxf(acc + fc1_b[o], 0.0f);
        }
        __syncthreads();

        if (wid < 10) {
            const float* w = fc2_w + wid * 128;
            float acc = fmaf(sm.d.h[lane], w[lane], 0.0f);
            acc = fmaf(sm.d.h[64 + lane], w[64 + lane], acc);
#pragma unroll
            for (int off = 32; off; off >>= 1) acc += __shfl_down(acc, off);
            if (lane == 0) out[b * 10 + wid] = acc + fc2_b[wid];
        }
    }
}

extern "C" void kernel_launch(void* const* d_in, const int* in_sizes, int n_in,
                              void* d_out, int out_size, void* d_ws, size_t ws_size,
                              hipStream_t stream) {
    const int*   ct0    = (const int*)d_in[0];
    const int*   cts    = (const int*)d_in[1];
    const int*   y      = (const int*)d_in[2];
    const int*   sk_y   = (const int*)d_in[3];
    const float* bias1  = (const float*)d_in[4];
    const float* bn1_g  = (const float*)d_in[5];
    const float* bn1_b  = (const float*)d_in[6];
    const float* bn1_m  = (const float*)d_in[7];
    const float* bn1_v  = (const float*)d_in[8];
    const float* conv2_w = (const float*)d_in[9];
    const float* conv2_b = (const float*)d_in[10];
    const float* bn2_g  = (const float*)d_in[11];
    const float* bn2_b  = (const float*)d_in[12];
    const float* bn2_m  = (const float*)d_in[13];
    const float* bn2_v  = (const float*)d_in[14];
    const float* conv3_w = (const float*)d_in[15];
    const float* conv3_b = (const float*)d_in[16];
    const float* bn3_g  = (const float*)d_in[17];
    const float* bn3_b  = (const float*)d_in[18];
    const float* bn3_m  = (const float*)d_in[19];
    const float* bn3_v  = (const float*)d_in[20];
    const float* fc1_w  = (const float*)d_in[21];
    const float* fc1_b  = (const float*)d_in[22];
    const float* fc2_w  = (const float*)d_in[23];
    const float* fc2_b  = (const float*)d_in[24];
    const int*   g_in   = (const int*)d_in[25];
    float* out = (float*)d_out;

    char* ws = (char*)d_ws;
    int16_t*  table  = (int16_t*)ws;
    unsigned* flags  = (unsigned*)(ws + FLAG_OFF);
    float* pooled = (float*)(ws + POOL_OFF);
    float* s2g    = (float*)(ws + S2G_OFF);
    float* s3g    = (float*)(ws + S3G_OFF);

    build_table<<<(TBLN + 255) / 256, 256, 0, stream>>>(g_in, table, flags);

    fused<<<NBLK, TPB, 0, stream>>>(
        ct0, cts, y, sk_y, bias1, bn1_g, bn1_b, bn1_m, bn1_v,
        conv2_w, conv2_b, bn2_g, bn2_b, bn2_m, bn2_v,
        conv3_w, conv3_b, bn3_g, bn3_b, bn3_m, bn3_v,
        fc1_w, fc1_b, fc2_w, fc2_b, table, pooled, s2g, s3g, out, flags);
}